// Round 3
// baseline (242.079 us; speedup 1.0000x reference)
//
#include <hip/hip_runtime.h>
#include <hip/hip_bf16.h>

// CausalAttention: B=4, S=2048, d=1024, single head, causal. fp32 I/O, bf16 MFMA inside.
//
// R11: overlap-structured 256^2 kernel for the K=1024 GEMMs (QKV mode 3, scores mode 1).
//      R10 audit: per-K-tile = 4940 cy = the SERIALIZED sum of MFMA (2484 cy/SIMD) and
//      LDS reads (192KB = 2260 cy/CU); m201-rate = overlapped max (~3300). R10's
//      BAR->reads->lgkm(0)->MFMA phases left LDS idle during barrier waits and stalled
//      each MFMA burst on its own full read burst.
//      New per-tile structure (2 barriers, one vmcnt wait, ledger-verified):
//        WAITV(4); BAR1;                      # A0,B0,A1,B1(t) landed (A0/B0(t+1) in flight)
//        rd af<-A0 (8), bf0<-B0 (4), bf1<-B1 (4);   # 16 ds_read_b128 queued at once
//        stg A1(t+1)->s1; stg B1(t+1)->s1;    # VMEM issue hidden under MFMA
//        MFMA q0 (af*bf0; compiler lgkm(4)), q1 (af*bf1; lgkm(0));
//        rd af<-A1 (8)   # register reuse, af0 dead after q1; drains under q1 tail
//        MFMA q2 (af*bf0), q3 (af*bf1);
//        BAR2; stg A0(t+2)->s; stg B0(t+2)->s;
//      Partial lgkm waits stagger LDS drain under MFMA; barrier-wait doubles as drain.
//      Stage safety: every stage's target region had its readers drained >=1 barrier
//      earlier (A1/B1 target the opposite slot; A0/B0(t+2) follow BAR2 > q0's drain).
//      WAITV(4) BEFORE BAR1 makes cross-wave staged data provably landed before reads.
//      vmcnt never 0 in-loop (T4); tail stages clamp to nt-1 (harmless rewrite of freed
//      regions, uniform ledger); WAITV(0) after loop. Frag VGPR = 64 (af reused) so
//      total ~ <200 arch + 128 acc AGPR fits 2 waves/SIMD budget (256/wave).
//
// Pipeline:
//   1) Wq/Wk/Wv fp32 -> bf16 transposed, stacked Wt [3072][1024]
//   2) x fp32 -> bf16 Xb
//   3) {Q,K,V} = Xb * Wt^T       (overlap 256^2, mode 3, grid 12x32)
//   4) zero rowsum; Vt = V^T per batch
//   5) E = masked-exp(Q*K^T/32) + rowsum   (overlap 256^2, mode 1, grid 8x8x4)
//   6) out(fp32) = (E * V) / rowsum        (R8 2-phase 128^2, mode 2, K clamped)

typedef __bf16 bf16_t;
typedef __bf16 bf16x8 __attribute__((ext_vector_type(8)));
typedef float f32x4 __attribute__((ext_vector_type(4)));

__device__ __forceinline__ void load_lds16(const bf16_t* g, bf16_t* l) {
  __builtin_amdgcn_global_load_lds(
      (__attribute__((address_space(1))) void*)(void*)g,
      (__attribute__((address_space(3))) void*)l,
      16, 0, 0);
}

#define WAITV(N) asm volatile("s_waitcnt vmcnt(" #N ")" ::: "memory")
#define BARM()   asm volatile("s_barrier" ::: "memory")

// ---------------- overlap-structured 256^2 kernel (modes 3 = qkv, 1 = scores) ------
// LDS swizzle: 16B chunk position p of row r holds global chunk p ^ (r&7);
// fragment reads are 2-way (free, m136). Conflicts measured 0 across R5-R10.
template <typename OT>
__global__ __launch_bounds__(512, 2)
void gemm_nt_ov(const bf16_t* __restrict__ A, const bf16_t* __restrict__ B,
                OT* __restrict__ C0, OT* __restrict__ C1, OT* __restrict__ C2,
                float* __restrict__ RS, int K, int ldc,
                long strideA, long strideB, long strideC, int mode)
{
  constexpr int SLOT = 2 * 256 * 64;   // bf16 elems per slot (A 16K + B 16K) = 32768

  // XCD-aware remap: pin all x-blocks of an A-panel (y,z) to one XCD.
  // Requires (gridDim.y*gridDim.z) % 8 == 0 -- true for both launches (32).
  const int gx = gridDim.x, gy = gridDim.y;
  const int NP = gy * gridDim.z;
  const int P  = NP >> 3;
  const int flat = blockIdx.x + gx * (blockIdx.y + gy * blockIdx.z);
  const int xcd  = flat & 7;
  const int ii   = flat >> 3;
  const int pan  = xcd * P + (ii % P);
  const int bx   = ii / P;
  int by = pan % gy;
  const int bz   = pan / gy;
  if (mode == 1) by = gy - 1 - by;                 // heavy-first
  const int rowBase = by * 256;
  const int colBase = bx * 256;
  if (mode == 1 && colBase >= rowBase + 256) return;

  __shared__ __align__(16) bf16_t sWS[2 * SLOT];   // 128 KiB

  A += (size_t)bz * strideA;
  B += (size_t)bz * strideB;
  float* rs_b = RS + (size_t)bz * 2048;

  const int tid  = threadIdx.x;
  const int wave = tid >> 6;
  const int lane = tid & 63;
  const int quad = lane >> 4;
  const int ln16 = lane & 15;
  const int wm = (wave & 1) * 64;                  // M offset within each 128-half
  const int wn = (wave >> 1) * 32;                 // N offset within each 128-half

  // staging: thread t covers row (t>>3) of a 64-row group, swizzled chunk (t&7)^(row&7)
  const int srow = tid >> 3;
  const int schk = (tid & 7) ^ (srow & 7);
  const bf16_t* pA = A + (size_t)(rowBase + srow) * K + schk * 8;
  const bf16_t* pB = B + (size_t)(colBase + srow) * K + schk * 8;
  bf16_t* const ldsW = sWS + wave * 512;           // per-wave linear dest base

  f32x4 acc[8][4] = {};
  const int nt = K >> 6;                           // 16 for both launches

  auto STG = [&](int side, int hh, int kt, int s) {
    const bf16_t* p = (side ? pB : pA) + (size_t)(hh * 128) * K + (size_t)kt * 64;
    bf16_t* l = ldsW + s * SLOT + side * 16384 + hh * 8192;
    load_lds16(p, l);
    load_lds16(p + (size_t)64 * K, l + 4096);
  };

  // prologue: A0(0) B0(0) A1(0) B1(0) A0(1) B0(1)  -- 12 load instrs/thread
  STG(0, 0, 0, 0); STG(1, 0, 0, 0); STG(0, 1, 0, 0); STG(1, 1, 0, 0);
  STG(0, 0, 1, 1); STG(1, 0, 1, 1);

  for (int t = 0; t < nt; ++t) {
    const int s  = t & 1;
    const int s1 = s ^ 1;
    const bf16_t* sAp = sWS + s * SLOT;
    const bf16_t* sBp = sAp + 16384;
    const int kt1 = (t + 1 < nt) ? t + 1 : nt - 1;   // tail: rewrite freed regions
    const int kt2 = (t + 2 < nt) ? t + 2 : nt - 1;

    WAITV(4);          // A0(t),B0(t),A1(t),B1(t) landed (all waves: wait precedes BAR1)
    BARM();            // BAR1: releases only after every wave's WAITV(4)

    bf16x8 af[2][4], bf0[2][2], bf1[2][2];
    // 16 ds_read_b128 queued at once; drain staggers under the MFMAs below.
#pragma unroll
    for (int kk = 0; kk < 2; kk++)
#pragma unroll
      for (int m = 0; m < 4; m++) {
        const int row = wm + m * 16 + ln16;
        af[kk][m] = *(const bf16x8*)(sAp + row * 64 + (((kk * 4 + quad) ^ (row & 7)) * 8));
      }
#pragma unroll
    for (int kk = 0; kk < 2; kk++)
#pragma unroll
      for (int f = 0; f < 2; f++) {
        const int row = wn + f * 16 + ln16;
        bf0[kk][f] = *(const bf16x8*)(sBp + row * 64 + (((kk * 4 + quad) ^ (row & 7)) * 8));
      }
#pragma unroll
    for (int kk = 0; kk < 2; kk++)
#pragma unroll
      for (int f = 0; f < 2; f++) {
        const int row = 128 + wn + f * 16 + ln16;
        bf1[kk][f] = *(const bf16x8*)(sBp + row * 64 + (((kk * 4 + quad) ^ (row & 7)) * 8));
      }
    // stage next tile's opposite-slot halves; issue before MFMA so HBM latency hides
    STG(0, 1, kt1, s1);          // A1(t+1): readers of s1.A1 drained before BAR1 ✓
    STG(1, 1, kt1, s1);          // B1(t+1): readers of s1.B1 drained before BAR1 ✓
    __builtin_amdgcn_sched_barrier(0);

    __builtin_amdgcn_s_setprio(1);
    // q0: af(A0) x bf0(B0)  [compiler waits lgkm for first 12 reads only]
#pragma unroll
    for (int kk = 0; kk < 2; kk++)
#pragma unroll
      for (int m = 0; m < 4; m++)
#pragma unroll
        for (int f = 0; f < 2; f++)
          acc[m][f] = __builtin_amdgcn_mfma_f32_16x16x32_bf16(af[kk][m], bf0[kk][f], acc[m][f], 0, 0, 0);
    // q1: af(A0) x bf1(B1)
#pragma unroll
    for (int kk = 0; kk < 2; kk++)
#pragma unroll
      for (int m = 0; m < 4; m++)
#pragma unroll
        for (int f = 0; f < 2; f++)
          acc[m][2 + f] = __builtin_amdgcn_mfma_f32_16x16x32_bf16(af[kk][m], bf1[kk][f], acc[m][2 + f], 0, 0, 0);
    __builtin_amdgcn_s_setprio(0);

    // reload af <- A1 (register reuse; WAR on q1's operands respected by compiler)
#pragma unroll
    for (int kk = 0; kk < 2; kk++)
#pragma unroll
      for (int m = 0; m < 4; m++) {
        const int row = 128 + wm + m * 16 + ln16;
        af[kk][m] = *(const bf16x8*)(sAp + row * 64 + (((kk * 4 + quad) ^ (row & 7)) * 8));
      }

    __builtin_amdgcn_s_setprio(1);
    // q2: af(A1) x bf0(B0)
#pragma unroll
    for (int kk = 0; kk < 2; kk++)
#pragma unroll
      for (int m = 0; m < 4; m++)
#pragma unroll
        for (int f = 0; f < 2; f++)
          acc[4 + m][f] = __builtin_amdgcn_mfma_f32_16x16x32_bf16(af[kk][m], bf0[kk][f], acc[4 + m][f], 0, 0, 0);
    // q3: af(A1) x bf1(B1)
#pragma unroll
    for (int kk = 0; kk < 2; kk++)
#pragma unroll
      for (int m = 0; m < 4; m++)
#pragma unroll
        for (int f = 0; f < 2; f++)
          acc[4 + m][2 + f] = __builtin_amdgcn_mfma_f32_16x16x32_bf16(af[kk][m], bf1[kk][f], acc[4 + m][2 + f], 0, 0, 0);
    __builtin_amdgcn_s_setprio(0);
    __builtin_amdgcn_sched_barrier(0);

    BARM();            // BAR2: all waves drained q0's reads of s.A0/s.B0 long before
    STG(0, 0, kt2, s); // A0(t+2) into just-freed region
    STG(1, 0, kt2, s); // B0(t+2)
  }
  WAITV(0);   // drain clamped tail stages before workgroup teardown

  // epilogue
  OT* Cw = C0;
  int cb = colBase;
  if (mode == 3) {
    const int which = colBase >> 10;                 // 256-col tiles never span matrices
    Cw = (which == 0) ? C0 : (which == 1) ? C1 : C2;
    cb = colBase & 1023;
  }
  Cw += (size_t)bz * strideC;

  // C/D layout: col = lane&15, row = quad*4 + r  [m89/m91]
#pragma unroll
  for (int m2 = 0; m2 < 8; m2++) {
#pragma unroll
    for (int r = 0; r < 4; r++) {
      const int row = rowBase + (m2 >> 2) * 128 + wm + (m2 & 3) * 16 + quad * 4 + r;
      float rsum = 0.0f;
#pragma unroll
      for (int f2 = 0; f2 < 4; f2++) {
        const int col = cb + (f2 >> 1) * 128 + wn + (f2 & 1) * 16 + ln16;
        float v = acc[m2][f2][r];
        if (mode == 1) {
          const float e = (col <= row) ? __expf(v * 0.03125f) : 0.0f;  // s/sqrt(1024)
          rsum += e;
          v = e;
        }
        Cw[(size_t)row * ldc + col] = (OT)v;
      }
      if (mode == 1) {
        rsum += __shfl_xor(rsum, 1, 64);
        rsum += __shfl_xor(rsum, 2, 64);
        rsum += __shfl_xor(rsum, 4, 64);
        rsum += __shfl_xor(rsum, 8, 64);
        if (ln16 == 0) atomicAdd(rs_b + row, rsum);
      }
    }
  }
}

// ---------------- R8 2-phase drain kernel (mode 2 = PV only) ----------------------
template <int BMv, int BNv, int NW, typename OT>
__global__ __launch_bounds__(NW * 64)
void gemm_nt_bf16(const bf16_t* __restrict__ A, const bf16_t* __restrict__ B,
                  OT* __restrict__ C0, OT* __restrict__ C1, OT* __restrict__ C2,
                  float* __restrict__ RS,
                  int M, int K, int ldc,
                  long strideA, long strideB, long strideC, int mode)
{
  constexpr int MW = BMv / 64;
  constexpr int RA = BMv / NW;
  constexpr int RB = BNv / NW;

  const int gx = gridDim.x, gy = gridDim.y;
  const int NP = gy * gridDim.z;
  const int P  = NP >> 3;
  const int flat = blockIdx.x + gx * (blockIdx.y + gy * blockIdx.z);
  const int xcd  = flat & 7;
  const int i    = flat >> 3;
  const int pan  = xcd * P + (i % P);
  const int bx   = i / P;
  int by = pan % gy;
  const int bz   = pan / gy;
  if (mode == 1 || mode == 2) by = gy - 1 - by;

  const int rowBase = by * BMv;
  const int colBase = bx * BNv;
  if (mode == 1 && colBase >= rowBase + BMv) return;

  __shared__ __align__(16) bf16_t sA[BMv * 64];
  __shared__ __align__(16) bf16_t sB[BNv * 64];

  A += (size_t)bz * strideA;
  B += (size_t)bz * strideB;
  float* rs_b = RS + (size_t)bz * 2048;

  const int tid  = threadIdx.x;
  const int wave = tid >> 6;
  const int lane = tid & 63;
  const int quad = lane >> 4;
  const int ln16 = lane & 15;

  const int wm = (wave % MW) * 64;
  const int wn = (wave / MW) * 64;

  const int rA = lane >> 3;
  const int sColOff = ((lane & 7) ^ rA) * 8;
  const bf16_t* pA = A + (size_t)(rowBase + wave * RA + rA) * K + sColOff;
  const bf16_t* pB = B + (size_t)(colBase + wave * RB + rA) * K + sColOff;
  bf16_t* ldsA = sA + wave * RA * 64;
  bf16_t* ldsB = sB + wave * RB * 64;

  f32x4 acc[4][4] = {};

  const int Kend = (mode == 2) ? (K < rowBase + BMv ? K : rowBase + BMv) : K;

  for (int k0 = 0; k0 < Kend; k0 += 64) {
#pragma unroll
    for (int j = 0; j < RA / 8; j++)
      load_lds16(pA + k0 + (size_t)(8 * j) * K, ldsA + j * 512);
#pragma unroll
    for (int j = 0; j < RB / 8; j++)
      load_lds16(pB + k0 + (size_t)(8 * j) * K, ldsB + j * 512);
    __syncthreads();

#pragma unroll
    for (int kk = 0; kk < 2; kk++) {
      bf16x8 af[4], bfr[4];
#pragma unroll
      for (int mt = 0; mt < 4; mt++) {
        const int row = wm + mt * 16 + ln16;
        af[mt] = *(const bf16x8*)(sA + row * 64 + (((kk * 4 + quad) ^ (row & 7)) * 8));
      }
#pragma unroll
      for (int nt = 0; nt < 4; nt++) {
        const int row = wn + nt * 16 + ln16;
        bfr[nt] = *(const bf16x8*)(sB + row * 64 + (((kk * 4 + quad) ^ (row & 7)) * 8));
      }
#pragma unroll
      for (int mt = 0; mt < 4; mt++)
#pragma unroll
        for (int nt = 0; nt < 4; nt++)
          acc[mt][nt] = __builtin_amdgcn_mfma_f32_16x16x32_bf16(af[mt], bfr[nt], acc[mt][nt], 0, 0, 0);
    }
    __syncthreads();
  }

  OT* Cw = C0;
  int cb = colBase;
  if (mode == 3) {
    const int which = colBase >> 10;
    Cw = (which == 0) ? C0 : (which == 1) ? C1 : C2;
    cb = colBase & 1023;
  }
  Cw += (size_t)bz * strideC;

#pragma unroll
  for (int mt = 0; mt < 4; mt++) {
#pragma unroll
    for (int r = 0; r < 4; r++) {
      const int row = rowBase + wm + mt * 16 + quad * 4 + r;
      float rsum = 0.0f;
      float rinv = 1.0f;
      if (mode == 2) rinv = 1.0f / rs_b[row];
#pragma unroll
      for (int nt = 0; nt < 4; nt++) {
        const int col = cb + wn + nt * 16 + ln16;
        float v = acc[mt][nt][r];
        if (mode == 1) {
          const float e = (col <= row) ? __expf(v * 0.03125f) : 0.0f;
          rsum += e;
          v = e;
        } else if (mode == 2) {
          v *= rinv;
        }
        Cw[(size_t)row * ldc + col] = (OT)v;
      }
      if (mode == 1) {
        rsum += __shfl_xor(rsum, 1, 64);
        rsum += __shfl_xor(rsum, 2, 64);
        rsum += __shfl_xor(rsum, 4, 64);
        rsum += __shfl_xor(rsum, 8, 64);
        if (ln16 == 0) atomicAdd(rs_b + row, rsum);
      }
    }
  }
}

// three fp32 [D][D] -> bf16 transposed, stacked [3D][D]; z selects source
__global__ __launch_bounds__(256)
void transpose_cvt3(const float* __restrict__ w0, const float* __restrict__ w1,
                    const float* __restrict__ w2, bf16_t* __restrict__ out, int D)
{
  const float* in = (blockIdx.z == 0) ? w0 : (blockIdx.z == 1) ? w1 : w2;
  bf16_t* o = out + (size_t)blockIdx.z * D * D;
  __shared__ float tile[32][33];
  const int c0 = blockIdx.x * 32, r0 = blockIdx.y * 32;
  const int tx = threadIdx.x, ty = threadIdx.y;  // (32, 8)
#pragma unroll
  for (int i = 0; i < 32; i += 8)
    tile[ty + i][tx] = in[(size_t)(r0 + ty + i) * D + (c0 + tx)];
  __syncthreads();
#pragma unroll
  for (int i = 0; i < 32; i += 8)
    o[(size_t)(c0 + ty + i) * D + (r0 + tx)] = (bf16_t)tile[tx][ty + i];
}

// bf16 [R][C] -> bf16 transposed [C][R]; batched via blockIdx.z
__global__ __launch_bounds__(256)
void transpose16(const unsigned short* __restrict__ in, unsigned short* __restrict__ out,
                 int R, int C)
{
  __shared__ unsigned short tile[32][33];
  const size_t bo = (size_t)blockIdx.z * R * C;
  const int c0 = blockIdx.x * 32, r0 = blockIdx.y * 32;
  const int tx = threadIdx.x, ty = threadIdx.y;  // (32, 8)
#pragma unroll
  for (int i = 0; i < 32; i += 8)
    tile[ty + i][tx] = in[bo + (size_t)(r0 + ty + i) * C + (c0 + tx)];
  __syncthreads();
#pragma unroll
  for (int i = 0; i < 32; i += 8)
    out[bo + (size_t)(c0 + ty + i) * R + (r0 + tx)] = tile[tx][ty + i];
}

// fp32 -> bf16 elementwise, 8/thread, vector load+store
__global__ __launch_bounds__(256)
void cvt_f32_bf16(const float* __restrict__ in, bf16_t* __restrict__ out, long n)
{
  long i = ((long)blockIdx.x * 256 + threadIdx.x) * 8;
  if (i + 7 < n) {
    float4 a = *(const float4*)(in + i);
    float4 b = *(const float4*)(in + i + 4);
    bf16x8 o;
    o[0] = (bf16_t)a.x; o[1] = (bf16_t)a.y; o[2] = (bf16_t)a.z; o[3] = (bf16_t)a.w;
    o[4] = (bf16_t)b.x; o[5] = (bf16_t)b.y; o[6] = (bf16_t)b.z; o[7] = (bf16_t)b.w;
    *(bf16x8*)(out + i) = o;
  }
}

__global__ __launch_bounds__(256)
void zero_f32(float* __restrict__ p, int n)
{
  const int i = blockIdx.x * 256 + threadIdx.x;
  if (i < n) p[i] = 0.0f;
}

extern "C" void kernel_launch(void* const* d_in, const int* in_sizes, int n_in,
                              void* d_out, int out_size, void* d_ws, size_t ws_size,
                              hipStream_t stream) {
  const float* x  = (const float*)d_in[0];
  const float* Wq = (const float*)d_in[1];
  const float* Wk = (const float*)d_in[2];
  const float* Wv = (const float*)d_in[3];
  float* out = (float*)d_out;

  const int Bb = 4, S = 2048, D = 1024;
  const int M = Bb * S;  // 8192

  // ws (bf16 elems): Q | K | Vt | Wt(3*D*D) | Xb | V   = 90,177,536 B (proven fit)
  // Sc (Bb*S*S == 2*M*D) aliases [Xb|V]; rowsum (32 KB f32) reuses Wt (dead post-QKV).
  bf16_t* ws = (bf16_t*)d_ws;
  bf16_t* Q   = ws;
  bf16_t* Kp  = Q  + (size_t)M * D;
  bf16_t* Vt  = Kp + (size_t)M * D;
  bf16_t* Wt  = Vt + (size_t)M * D;          // [3072][1024] stacked
  bf16_t* Xb  = Wt + 3 * (size_t)D * D;
  bf16_t* V   = Xb + (size_t)M * D;
  bf16_t* Sc  = Xb;
  float*  rowsum = (float*)Wt;               // Bb*S floats

  const dim3 tb(32, 8);

  // 1) W fp32 -> bf16 transposed, stacked
  transpose_cvt3<<<dim3(D / 32, D / 32, 3), tb, 0, stream>>>(Wq, Wk, Wv, Wt, D);

  // 2) x -> bf16
  cvt_f32_bf16<<<dim3((M * D) / (256 * 8)), dim3(256), 0, stream>>>(x, Xb, (long)M * D);

  // 3) fused projections: {Q,K,V} = Xb * Wt^T  (grid 12x32, 384 tiles)
  gemm_nt_ov<bf16_t><<<dim3(3 * D / 256, M / 256, 1), dim3(512), 0, stream>>>(
      Xb, Wt, Q, Kp, V, rowsum, D, D, 0, 0, 0, 3);

  // 4) zero rowsum (Wt dead now); Vt per batch
  zero_f32<<<dim3(M / 256), dim3(256), 0, stream>>>(rowsum, M);
  transpose16<<<dim3(D / 32, S / 32, Bb), tb, 0, stream>>>((const unsigned short*)V, (unsigned short*)Vt, S, D);

  // 5) E = masked-exp(Q*K^T/32) + rowsum  (grid 8x8x4, 144 active tiles)
  gemm_nt_ov<bf16_t><<<dim3(S / 256, S / 256, Bb), dim3(512), 0, stream>>>(
      Q, Kp, Sc, Sc, Sc, rowsum, D, S, (long)S * D, (long)S * D, (long)S * S, 1);

  // 6) out(fp32) = (E*V)/rowsum  (2-phase; grid 8 x 16 x 4; 64 panels -> 8/XCD)
  gemm_nt_bf16<128, 128, 4, float><<<dim3(D / 128, S / 128, Bb), dim3(256), 0, stream>>>(
      Sc, Vt, out, out, out, rowsum, S, S, D, (long)S * S, (long)D * S, (long)S * D, 2);
}

// Round 4
// 236.785 us; speedup vs baseline: 1.0224x; 1.0224x over previous
//
#include <hip/hip_runtime.h>
#include <hip/hip_bf16.h>

// CausalAttention: B=4, S=2048, d=1024, single head, causal. fp32 I/O, bf16 MFMA inside.
//
// R12: strategy reset to the R8 champion structure (2-barrier m97-style loop, 3 blk/CU
//      TLP does the latency hiding -- R9/R10/R11 pipeline restructures all lost to it).
//      Two measured-precedent changes only:
//      (a) QKV: 256x128 -> 128x128 4-wave (m97-proven tile; guide tile-space
//          128^2=912 TF > 256x128=823). Grid 24x64 = 1536 blocks = 6.0 exact rounds,
//          48 KB LDS -> 3 blocks/CU.
//      (b) scores: 128^2 tiles + FLAT triangular grid with exact XCD balance.
//          Per batch, panels pair (by, 15-by) -> 17 tiles/pair; 8 pairs -> 68 tiles
//          per XCD exactly (544 blocks, %8==0). Replaces the 512-block grid whose
//          288 actives gave a 2-3-round makespan vs ideal 1.125.
//      (c) MODE is now a template arg -> distinct mangled names for QKV/scores/PV so
//          rocprof separates them next round.
//
// Pipeline:
//   1) Wq/Wk/Wv fp32 -> bf16 transposed, stacked Wt [3072][1024]
//   2) x fp32 -> bf16 Xb
//   3) {Q,K,V} = Xb * Wt^T       (MODE 3, 128^2, grid 24x64)
//   4) zero rowsum; Vt = V^T per batch
//   5) E = masked-exp(Q*K^T/32), rowsum accumulated   (MODE 1, 128^2, flat tri grid 544)
//   6) out(fp32) = (E * V) / rowsum                   (MODE 2, 128^2, K clamped)

typedef __bf16 bf16_t;
typedef __bf16 bf16x8 __attribute__((ext_vector_type(8)));
typedef float f32x4 __attribute__((ext_vector_type(4)));

__device__ __forceinline__ void load_lds16(const bf16_t* g, bf16_t* l) {
  __builtin_amdgcn_global_load_lds(
      (__attribute__((address_space(1))) void*)(void*)g,
      (__attribute__((address_space(3))) void*)l,
      16, 0, 0);
}

// C[m][n] = sum_k A[m][k]*B[n][k]  (A:[M][K], B:[N][K] row-major bf16)
// MODE: 1 scores: flat triangular grid, epilogue mask+exp+rowsum
//       2 pv: clamp K at rowBase+BMv, epilogue scale by 1/rowsum | 3 fused qkv split
// LDS swizzle: 16B chunk position p of row r holds global chunk p ^ (r&7);
// fragment reads hit all 32 banks 2-way (free, m136). Conflicts measured 0 (R5-R11).
template <int BMv, int BNv, int NW, int MODE, typename OT>
__global__ __launch_bounds__(NW * 64)
void gemm_nt_bf16(const bf16_t* __restrict__ A, const bf16_t* __restrict__ B,
                  OT* __restrict__ C0, OT* __restrict__ C1, OT* __restrict__ C2,
                  float* __restrict__ RS,
                  int M, int K, int ldc,
                  long strideA, long strideB, long strideC)
{
  constexpr int MW = BMv / 64;       // wave grid: MW x (NW/MW)
  constexpr int RA = BMv / NW;       // rows staged per wave (A)
  constexpr int RB = BNv / NW;       // rows staged per wave (B)

  int bx, by, bz;
  if constexpr (MODE == 1) {
    // Flat XCD-balanced lower-triangle enumeration (S=2048, 128-tiles, 16 panels/batch).
    // XCD x (= blockIdx.x & 7, m09 round-robin) owns panels {x, 15-x} of every batch:
    // weight (x+1) + (16-x) = 17 tiles per batch -> 68 per XCD, exact balance.
    const int f = blockIdx.x;          // 544 blocks
    const int x = f & 7;
    const int j = f >> 3;              // [0, 68)
    bz = j / 17;
    const int r = j % 17;
    by = (r <= x) ? x : 15 - x;
    bx = (r <= x) ? r : r - (x + 1);
  } else {
    // XCD-aware remap: pin all x-blocks of an A-panel (y,z) to one XCD.
    // Requires (gridDim.y*gridDim.z) % 8 == 0 -- true for both launches (64).
    const int gx = gridDim.x, gy = gridDim.y;
    const int NP = gy * gridDim.z;
    const int P  = NP >> 3;                         // panels per XCD
    const int flat = blockIdx.x + gx * (blockIdx.y + gy * blockIdx.z);
    const int xcd  = flat & 7;
    const int i    = flat >> 3;
    const int pan  = xcd * P + (i % P);
    bx = i / P;
    by = pan % gy;
    bz = pan / gy;
    if (MODE == 2) by = gy - 1 - by;                // heavy-first for K-clamp pairing
  }

  const int rowBase = by * BMv;
  const int colBase = bx * BNv;

  __shared__ __align__(16) bf16_t sA[BMv * 64];
  __shared__ __align__(16) bf16_t sB[BNv * 64];

  A += (size_t)bz * strideA;
  B += (size_t)bz * strideB;
  float* rs_b = RS + (size_t)bz * 2048;

  const int tid  = threadIdx.x;
  const int wave = tid >> 6;
  const int lane = tid & 63;
  const int quad = lane >> 4;
  const int ln16 = lane & 15;

  const int wm = (wave % MW) * 64;
  const int wn = (wave / MW) * 64;

  const int rA = lane >> 3;                       // 0..7 row-in-group
  const int sColOff = ((lane & 7) ^ rA) * 8;      // swizzled chunk offset (elems)
  const bf16_t* pA = A + (size_t)(rowBase + wave * RA + rA) * K + sColOff;
  const bf16_t* pB = B + (size_t)(colBase + wave * RB + rA) * K + sColOff;
  bf16_t* ldsA = sA + wave * RA * 64;
  bf16_t* ldsB = sB + wave * RB * 64;

  f32x4 acc[4][4] = {};

  const int Kend = (MODE == 2) ? (K < rowBase + BMv ? K : rowBase + BMv) : K;

  for (int k0 = 0; k0 < Kend; k0 += 64) {
#pragma unroll
    for (int j = 0; j < RA / 8; j++)
      load_lds16(pA + k0 + (size_t)(8 * j) * K, ldsA + j * 512);
#pragma unroll
    for (int j = 0; j < RB / 8; j++)
      load_lds16(pB + k0 + (size_t)(8 * j) * K, ldsB + j * 512);
    __syncthreads();   // drains vmcnt for all waves

#pragma unroll
    for (int kk = 0; kk < 2; kk++) {
      bf16x8 af[4], bfr[4];
#pragma unroll
      for (int mt = 0; mt < 4; mt++) {
        const int row = wm + mt * 16 + ln16;
        af[mt] = *(const bf16x8*)(sA + row * 64 + (((kk * 4 + quad) ^ (row & 7)) * 8));
      }
#pragma unroll
      for (int nt = 0; nt < 4; nt++) {
        const int row = wn + nt * 16 + ln16;
        bfr[nt] = *(const bf16x8*)(sB + row * 64 + (((kk * 4 + quad) ^ (row & 7)) * 8));
      }
#pragma unroll
      for (int mt = 0; mt < 4; mt++)
#pragma unroll
        for (int nt = 0; nt < 4; nt++)
          acc[mt][nt] = __builtin_amdgcn_mfma_f32_16x16x32_bf16(af[mt], bfr[nt], acc[mt][nt], 0, 0, 0);
    }
    __syncthreads();
  }

  // output target: MODE 3 splits by 1024-col groups (uniform per block)
  OT* Cw = C0;
  int cb = colBase;
  if constexpr (MODE == 3) {
    const int which = colBase >> 10;               // 128-col tiles never span matrices
    Cw = (which == 0) ? C0 : (which == 1) ? C1 : C2;
    cb = colBase & 1023;
  }
  Cw += (size_t)bz * strideC;

  // epilogue: C/D layout col = lane&15, row = quad*4 + r  [measured m89/m91]
#pragma unroll
  for (int mt = 0; mt < 4; mt++) {
#pragma unroll
    for (int r = 0; r < 4; r++) {
      const int row = rowBase + wm + mt * 16 + quad * 4 + r;
      float rsum = 0.0f;
      float rinv = 1.0f;
      if (MODE == 2) rinv = 1.0f / rs_b[row];
#pragma unroll
      for (int nt = 0; nt < 4; nt++) {
        const int col = cb + wn + nt * 16 + ln16;
        float v = acc[mt][nt][r];
        if (MODE == 1) {
          const float e = (col <= row) ? __expf(v * 0.03125f) : 0.0f;  // s/sqrt(1024)
          rsum += e;
          v = e;
        } else if (MODE == 2) {
          v *= rinv;
        }
        Cw[(size_t)row * ldc + col] = (OT)v;
      }
      if (MODE == 1) {
        rsum += __shfl_xor(rsum, 1, 64);
        rsum += __shfl_xor(rsum, 2, 64);
        rsum += __shfl_xor(rsum, 4, 64);
        rsum += __shfl_xor(rsum, 8, 64);
        if (ln16 == 0) atomicAdd(rs_b + row, rsum);
      }
    }
  }
}

// three fp32 [D][D] -> bf16 transposed, stacked [3D][D]; z selects source
__global__ __launch_bounds__(256)
void transpose_cvt3(const float* __restrict__ w0, const float* __restrict__ w1,
                    const float* __restrict__ w2, bf16_t* __restrict__ out, int D)
{
  const float* in = (blockIdx.z == 0) ? w0 : (blockIdx.z == 1) ? w1 : w2;
  bf16_t* o = out + (size_t)blockIdx.z * D * D;
  __shared__ float tile[32][33];
  const int c0 = blockIdx.x * 32, r0 = blockIdx.y * 32;
  const int tx = threadIdx.x, ty = threadIdx.y;  // (32, 8)
#pragma unroll
  for (int i = 0; i < 32; i += 8)
    tile[ty + i][tx] = in[(size_t)(r0 + ty + i) * D + (c0 + tx)];
  __syncthreads();
#pragma unroll
  for (int i = 0; i < 32; i += 8)
    o[(size_t)(c0 + ty + i) * D + (r0 + tx)] = (bf16_t)tile[tx][ty + i];
}

// bf16 [R][C] -> bf16 transposed [C][R]; batched via blockIdx.z
__global__ __launch_bounds__(256)
void transpose16(const unsigned short* __restrict__ in, unsigned short* __restrict__ out,
                 int R, int C)
{
  __shared__ unsigned short tile[32][33];
  const size_t bo = (size_t)blockIdx.z * R * C;
  const int c0 = blockIdx.x * 32, r0 = blockIdx.y * 32;
  const int tx = threadIdx.x, ty = threadIdx.y;  // (32, 8)
#pragma unroll
  for (int i = 0; i < 32; i += 8)
    tile[ty + i][tx] = in[bo + (size_t)(r0 + ty + i) * C + (c0 + tx)];
  __syncthreads();
#pragma unroll
  for (int i = 0; i < 32; i += 8)
    out[bo + (size_t)(c0 + ty + i) * R + (r0 + tx)] = tile[tx][ty + i];
}

// fp32 -> bf16 elementwise, 8/thread, vector load+store
__global__ __launch_bounds__(256)
void cvt_f32_bf16(const float* __restrict__ in, bf16_t* __restrict__ out, long n)
{
  long i = ((long)blockIdx.x * 256 + threadIdx.x) * 8;
  if (i + 7 < n) {
    float4 a = *(const float4*)(in + i);
    float4 b = *(const float4*)(in + i + 4);
    bf16x8 o;
    o[0] = (bf16_t)a.x; o[1] = (bf16_t)a.y; o[2] = (bf16_t)a.z; o[3] = (bf16_t)a.w;
    o[4] = (bf16_t)b.x; o[5] = (bf16_t)b.y; o[6] = (bf16_t)b.z; o[7] = (bf16_t)b.w;
    *(bf16x8*)(out + i) = o;
  }
}

__global__ __launch_bounds__(256)
void zero_f32(float* __restrict__ p, int n)
{
  const int i = blockIdx.x * 256 + threadIdx.x;
  if (i < n) p[i] = 0.0f;
}

extern "C" void kernel_launch(void* const* d_in, const int* in_sizes, int n_in,
                              void* d_out, int out_size, void* d_ws, size_t ws_size,
                              hipStream_t stream) {
  const float* x  = (const float*)d_in[0];
  const float* Wq = (const float*)d_in[1];
  const float* Wk = (const float*)d_in[2];
  const float* Wv = (const float*)d_in[3];
  float* out = (float*)d_out;

  const int Bb = 4, S = 2048, D = 1024;
  const int M = Bb * S;  // 8192

  // ws (bf16 elems): Q | K | Vt | Wt(3*D*D) | Xb | V   = 90,177,536 B (proven fit)
  // Sc (Bb*S*S == 2*M*D) aliases [Xb|V]; rowsum (32 KB f32) reuses Wt (dead post-QKV).
  bf16_t* ws = (bf16_t*)d_ws;
  bf16_t* Q   = ws;
  bf16_t* Kp  = Q  + (size_t)M * D;
  bf16_t* Vt  = Kp + (size_t)M * D;
  bf16_t* Wt  = Vt + (size_t)M * D;          // [3072][1024] stacked
  bf16_t* Xb  = Wt + 3 * (size_t)D * D;
  bf16_t* V   = Xb + (size_t)M * D;
  bf16_t* Sc  = Xb;
  float*  rowsum = (float*)Wt;               // Bb*S floats

  const dim3 tb(32, 8);

  // 1) W fp32 -> bf16 transposed, stacked
  transpose_cvt3<<<dim3(D / 32, D / 32, 3), tb, 0, stream>>>(Wq, Wk, Wv, Wt, D);

  // 2) x -> bf16
  cvt_f32_bf16<<<dim3((M * D) / (256 * 8)), dim3(256), 0, stream>>>(x, Xb, (long)M * D);

  // 3) fused projections: {Q,K,V} = Xb * Wt^T  (128^2; grid 24x64 = 1536 = 6.0 rounds)
  gemm_nt_bf16<128, 128, 4, 3, bf16_t><<<dim3(3 * D / 128, M / 128, 1), dim3(256), 0, stream>>>(
      Xb, Wt, Q, Kp, V, rowsum, M, D, D, 0, 0, 0);

  // 4) zero rowsum (Wt dead now); Vt per batch
  zero_f32<<<dim3(M / 256), dim3(256), 0, stream>>>(rowsum, M);
  transpose16<<<dim3(D / 32, S / 32, Bb), tb, 0, stream>>>((const unsigned short*)V, (unsigned short*)Vt, S, D);

  // 5) E = masked-exp(Q*K^T/32) + rowsum  (flat triangular grid: 544 tiles, 68/XCD exact)
  gemm_nt_bf16<128, 128, 4, 1, bf16_t><<<dim3(544, 1, 1), dim3(256), 0, stream>>>(
      Q, Kp, Sc, Sc, Sc, rowsum, S, D, S, (long)S * D, (long)S * D, (long)S * S);

  // 6) out(fp32) = (E*V)/rowsum  (grid 8 x 16 x 4; 64 panels -> 8/XCD)
  gemm_nt_bf16<128, 128, 4, 2, float><<<dim3(D / 128, S / 128, Bb), dim3(256), 0, stream>>>(
      Sc, Vt, out, out, out, rowsum, S, S, D, (long)S * S, (long)D * S, (long)S * D);
}